// Round 3
// baseline (996.702 us; speedup 1.0000x reference)
//
#include <hip/hip_runtime.h>
#include <hip/hip_bf16.h>

#define NN   100000
#define KD   500
#define KP   512    // K padded (W zero-filled)
#define HID  64
#define LWS  264    // LDS row stride (bf16 elems) for a 256-wide K chunk
#define GS   24     // g row stride (floats): B at cols 0..9, C at cols 12..21

typedef short frag8 __attribute__((ext_vector_type(8)));
typedef float f32x4 __attribute__((ext_vector_type(4)));

static __device__ __forceinline__ unsigned short f2b(float f) {
    return __builtin_bit_cast(unsigned short, __float2bfloat16(f));
}

// ---------------- Kernel 0: W1 fp32 -> bf16, zero-padded to K=512 ----------------
__global__ __launch_bounds__(256) void k0_w1bf(const float* __restrict__ W1,
                                               unsigned short* __restrict__ W1bf)
{
    const int i = blockIdx.x * 256 + threadIdx.x;   // 0..32767
    const int c = i >> 9;        // col 0..63
    const int k = i & 511;
    const float v = (k < KD) ? W1[c * KD + k] : 0.f;
    W1bf[i] = f2b(v);
}

// ---------------- Kernel 1: h = relu(x @ W1^T), bf16 MFMA ----------------
// 256 threads = 4 waves; each wave computes a 16-row x 64-col tile; block = 64 rows.
// W1bf staged to LDS in two 256-K chunks (pure copies). x loaded global->reg with
// one-step prefetch, converted fp32->bf16 in-reg.
__global__ __launch_bounds__(256, 4) void k1_mfma(const float* __restrict__ x,
                                                  const unsigned short* __restrict__ W1bf,
                                                  float* __restrict__ h, int n)
{
    __shared__ unsigned short lw[64 * LWS];
    const int tid   = threadIdx.x;
    const int lane  = tid & 63;
    const int wid   = tid >> 6;
    const int l15   = lane & 15;
    const int l4    = lane >> 4;     // 0..3
    const int koffl = 8 * l4;        // lane's k sub-offset within a 32-k step

    const long rowBlk = (long)blockIdx.x * 64;
    long ra = rowBlk + wid * 16 + l15;
    if (ra >= n) ra = n - 1;                 // clamp; stores are guarded
    const float* xp = x + ra * KD + koffl;

    f32x4 acc[4] = {};
    const float4 z = make_float4(0.f, 0.f, 0.f, 0.f);

    for (int c = 0; c < 2; ++c) {
        if (c) __syncthreads();
        // stage W1bf[64][c*256 .. +256) -> lw (16B copies, no conversion)
        #pragma unroll
        for (int it = 0; it < 8; ++it) {
            const int idx = tid + it * 256;      // 0..2047
            const int r   = idx >> 5;            // 0..63
            const int q   = idx & 31;            // ushort8 index
            *(uint4*)&lw[r * LWS + q * 8] =
                *(const uint4*)&W1bf[r * KP + c * 256 + q * 8];
        }
        __syncthreads();

        // prefetch ks=0 of this chunk
        int k0 = c * 256;
        float4 lo = (k0 + koffl     < KD) ? *(const float4*)(xp + k0)     : z;
        float4 hi = (k0 + koffl + 4 < KD) ? *(const float4*)(xp + k0 + 4) : z;

        #pragma unroll
        for (int ks = 0; ks < 8; ++ks) {
            float4 nlo = z, nhi = z;
            if (ks < 7) {
                const int kn = c * 256 + (ks + 1) * 32;
                nlo = (kn + koffl     < KD) ? *(const float4*)(xp + kn)     : z;
                nhi = (kn + koffl + 4 < KD) ? *(const float4*)(xp + kn + 4) : z;
            }
            frag8 a;
            a[0]=f2b(lo.x); a[1]=f2b(lo.y); a[2]=f2b(lo.z); a[3]=f2b(lo.w);
            a[4]=f2b(hi.x); a[5]=f2b(hi.y); a[6]=f2b(hi.z); a[7]=f2b(hi.w);
            const int koffw = ks * 32 + koffl;
            #pragma unroll
            for (int g = 0; g < 4; ++g) {
                const frag8 b = *(const frag8*)&lw[(g * 16 + l15) * LWS + koffw];
                acc[g] = __builtin_amdgcn_mfma_f32_16x16x32_bf16(a, b, acc[g], 0, 0, 0);
            }
            lo = nlo; hi = nhi;
        }
    }

    // epilogue: relu + store. D layout: col = lane&15 (W col), row = (lane>>4)*4 + reg (x row)
    #pragma unroll
    for (int r = 0; r < 4; ++r) {
        const long row = rowBlk + wid * 16 + l4 * 4 + r;
        if (row < n) {
            #pragma unroll
            for (int g = 0; g < 4; ++g)
                h[row * HID + g * 16 + l15] = fmaxf(acc[g][r], 0.f);
        }
    }
}

// ---------------- Kernel 2: projections ----------------
// out = h @ WfA^T ; g[:,0:10) = h @ WfB^T ; g[:,12:22) = h @ WfC^T
__global__ __launch_bounds__(256) void k2_proj(const float* __restrict__ h,
                                               const float* __restrict__ Wf,
                                               float* __restrict__ out,
                                               float* __restrict__ g, int n)
{
    __shared__ float lwf[10 * 196];
    const int tid = threadIdx.x;
    for (int idx = tid; idx < 480; idx += 256) {
        const int j = idx / 48;
        const int q = idx - j * 48;
        const float4 v = *(const float4*)&Wf[j * 192 + 4 * q];
        *(float4*)&lwf[j * 196 + 4 * q] = v;
    }
    __syncthreads();

    const long row = (long)blockIdx.x * 8 + (tid >> 5);
    const int  j   = tid & 31;
    if (row < n && j < 30) {
        const int wrow = (j < 10) ? j : ((j < 20) ? j - 10 : j - 20);
        const int coff = (j < 10) ? 0 : ((j < 20) ? 64 : 128);
        const float* wp = &lwf[wrow * 196 + coff];
        const float* hp = &h[row * HID];
        float s = 0.f;
        #pragma unroll
        for (int q = 0; q < 16; ++q) {
            const float4 hv = *(const float4*)&hp[4 * q];
            const float4 wv = *(const float4*)&wp[4 * q];
            s += hv.x * wv.x + hv.y * wv.y + hv.z * wv.z + hv.w * wv.w;
        }
        if (j < 10)      out[row * 10 + j] = s;
        else if (j < 20) g[row * GS + (j - 10)] = s;
        else             g[row * GS + 12 + (j - 20)] = s;
    }
}

// ---------------- Kernel 3: merged edge scatter (both hops) ----------------
// out[dst,0:10) += val * g[src, goff+0:10),  one thread per edge
__global__ __launch_bounds__(256) void k_scatter(const int* __restrict__ src1,
                                                 const int* __restrict__ dst1,
                                                 const float* __restrict__ val1, int nnz1,
                                                 const int* __restrict__ src2,
                                                 const int* __restrict__ dst2,
                                                 const float* __restrict__ val2, int nnz2,
                                                 const float* __restrict__ g,
                                                 float* __restrict__ out)
{
    const int e = blockIdx.x * 256 + threadIdx.x;
    const int* sp; const int* dp; const float* vp; int goff, idx;
    if (e < nnz1) { sp = src1; dp = dst1; vp = val1; goff = 0;  idx = e; }
    else {
        idx = e - nnz1;
        if (idx >= nnz2) return;
        sp = src2; dp = dst2; vp = val2; goff = 12;
    }
    const int   s = sp[idx];
    const int   d = dp[idx];
    const float v = vp[idx];
    const float* gp = g + (size_t)s * GS + goff;
    const float4 g0 = *(const float4*)gp;
    const float4 g1 = *(const float4*)(gp + 4);
    const float2 g2 = *(const float2*)(gp + 8);
    float* op = out + (size_t)d * 10;
    unsafeAtomicAdd(op + 0, v * g0.x);
    unsafeAtomicAdd(op + 1, v * g0.y);
    unsafeAtomicAdd(op + 2, v * g0.z);
    unsafeAtomicAdd(op + 3, v * g0.w);
    unsafeAtomicAdd(op + 4, v * g1.x);
    unsafeAtomicAdd(op + 5, v * g1.y);
    unsafeAtomicAdd(op + 6, v * g1.z);
    unsafeAtomicAdd(op + 7, v * g1.w);
    unsafeAtomicAdd(op + 8, v * g2.x);
    unsafeAtomicAdd(op + 9, v * g2.y);
}

extern "C" void kernel_launch(void* const* d_in, const int* in_sizes, int n_in,
                              void* d_out, int out_size, void* d_ws, size_t ws_size,
                              hipStream_t stream)
{
    const float* x    = (const float*)d_in[0];
    const float* W1   = (const float*)d_in[1];
    const float* Wf   = (const float*)d_in[2];
    const int*   src1 = (const int*)d_in[3];
    const int*   dst1 = (const int*)d_in[4];
    const float* val1 = (const float*)d_in[5];
    const int*   src2 = (const int*)d_in[6];
    const int*   dst2 = (const int*)d_in[7];
    const float* val2 = (const float*)d_in[8];
    const int nnz1 = in_sizes[3];
    const int nnz2 = in_sizes[6];
    const int n = NN;

    unsigned short* W1bf = (unsigned short*)d_ws;            // [64][512] bf16 = 64 KB
    float* h   = (float*)((char*)d_ws + 64 * KP * 2);        // [NN][64]  = 25.6 MB
    float* g   = h + (size_t)NN * HID;                       // [NN][24]  =  9.6 MB
    float* out = (float*)d_out;                              // [NN][10]

    k0_w1bf<<<128, 256, 0, stream>>>(W1, W1bf);
    k1_mfma<<<(n + 63) / 64, 256, 0, stream>>>(x, W1bf, h, n);
    k2_proj<<<(n + 7) / 8, 256, 0, stream>>>(h, Wf, out, g, n);
    const int ne = nnz1 + nnz2;
    k_scatter<<<(ne + 255) / 256, 256, 0, stream>>>(src1, dst1, val1, nnz1,
                                                    src2, dst2, val2, nnz2, g, out);
}

// Round 4
// 228.277 us; speedup vs baseline: 4.3662x; 4.3662x over previous
//
#include <hip/hip_runtime.h>
#include <hip/hip_bf16.h>

#define NN   100000
#define KD   500
#define KP   512    // K padded (W zero-filled)
#define HID  64
#define LWS  264    // LDS row stride (bf16 elems) for a 256-wide K chunk
#define GS   24     // g row stride (floats): B at cols 0..9, C at cols 12..21

typedef short frag8 __attribute__((ext_vector_type(8)));
typedef float f32x4 __attribute__((ext_vector_type(4)));

static __device__ __forceinline__ unsigned short f2b(float f) {
    return __builtin_bit_cast(unsigned short, __float2bfloat16(f));
}

// ---------------- Kernel 0: W1 fp32 -> bf16, zero-padded to K=512 ----------------
__global__ __launch_bounds__(256) void k0_w1bf(const float* __restrict__ W1,
                                               unsigned short* __restrict__ W1bf)
{
    const int i = blockIdx.x * 256 + threadIdx.x;   // 0..32767
    const int c = i >> 9;        // col 0..63
    const int k = i & 511;
    const float v = (k < KD) ? W1[c * KD + k] : 0.f;
    W1bf[i] = f2b(v);
}

// ---------------- Kernel 1: h = relu(x @ W1^T), bf16 MFMA ----------------
// 256 threads = 4 waves; each wave computes a 16-row x 64-col tile; block = 64 rows.
__global__ __launch_bounds__(256, 4) void k1_mfma(const float* __restrict__ x,
                                                  const unsigned short* __restrict__ W1bf,
                                                  float* __restrict__ h, int n)
{
    __shared__ unsigned short lw[64 * LWS];
    const int tid   = threadIdx.x;
    const int lane  = tid & 63;
    const int wid   = tid >> 6;
    const int l15   = lane & 15;
    const int l4    = lane >> 4;     // 0..3
    const int koffl = 8 * l4;        // lane's k sub-offset within a 32-k step

    const long rowBlk = (long)blockIdx.x * 64;
    long ra = rowBlk + wid * 16 + l15;
    if (ra >= n) ra = n - 1;                 // clamp; stores are guarded
    const float* xp = x + ra * KD + koffl;

    f32x4 acc[4] = {};
    const float4 z = make_float4(0.f, 0.f, 0.f, 0.f);

    for (int c = 0; c < 2; ++c) {
        if (c) __syncthreads();
        // stage W1bf[64][c*256 .. +256) -> lw (16B copies, no conversion)
        #pragma unroll
        for (int it = 0; it < 8; ++it) {
            const int idx = tid + it * 256;      // 0..2047
            const int r   = idx >> 5;            // 0..63
            const int q   = idx & 31;            // ushort8 index
            *(uint4*)&lw[r * LWS + q * 8] =
                *(const uint4*)&W1bf[r * KP + c * 256 + q * 8];
        }
        __syncthreads();

        // prefetch ks=0 of this chunk
        int k0 = c * 256;
        float4 lo = (k0 + koffl     < KD) ? *(const float4*)(xp + k0)     : z;
        float4 hi = (k0 + koffl + 4 < KD) ? *(const float4*)(xp + k0 + 4) : z;

        #pragma unroll
        for (int ks = 0; ks < 8; ++ks) {
            float4 nlo = z, nhi = z;
            if (ks < 7) {
                const int kn = c * 256 + (ks + 1) * 32;
                nlo = (kn + koffl     < KD) ? *(const float4*)(xp + kn)     : z;
                nhi = (kn + koffl + 4 < KD) ? *(const float4*)(xp + kn + 4) : z;
            }
            frag8 a;
            a[0]=f2b(lo.x); a[1]=f2b(lo.y); a[2]=f2b(lo.z); a[3]=f2b(lo.w);
            a[4]=f2b(hi.x); a[5]=f2b(hi.y); a[6]=f2b(hi.z); a[7]=f2b(hi.w);
            const int koffw = ks * 32 + koffl;
            #pragma unroll
            for (int g = 0; g < 4; ++g) {
                const frag8 b = *(const frag8*)&lw[(g * 16 + l15) * LWS + koffw];
                acc[g] = __builtin_amdgcn_mfma_f32_16x16x32_bf16(a, b, acc[g], 0, 0, 0);
            }
            lo = nlo; hi = nhi;
        }
    }

    // epilogue: relu + store. D layout: col = lane&15 (W col), row = (lane>>4)*4 + reg (x row)
    #pragma unroll
    for (int r = 0; r < 4; ++r) {
        const long row = rowBlk + wid * 16 + l4 * 4 + r;
        if (row < n) {
            #pragma unroll
            for (int g = 0; g < 4; ++g)
                h[row * HID + g * 16 + l15] = fmaxf(acc[g][r], 0.f);
        }
    }
}

// ---------------- Kernel 2: projections ----------------
// out = h @ WfA^T ; g[:,0:10) = h @ WfB^T ; g[:,12:22) = h @ WfC^T
__global__ __launch_bounds__(256) void k2_proj(const float* __restrict__ h,
                                               const float* __restrict__ Wf,
                                               float* __restrict__ out,
                                               float* __restrict__ g, int n)
{
    __shared__ float lwf[10 * 196];
    const int tid = threadIdx.x;
    for (int idx = tid; idx < 480; idx += 256) {
        const int j = idx / 48;
        const int q = idx - j * 48;
        const float4 v = *(const float4*)&Wf[j * 192 + 4 * q];
        *(float4*)&lwf[j * 196 + 4 * q] = v;
    }
    __syncthreads();

    const long row = (long)blockIdx.x * 8 + (tid >> 5);
    const int  j   = tid & 31;
    if (row < n && j < 30) {
        const int wrow = (j < 10) ? j : ((j < 20) ? j - 10 : j - 20);
        const int coff = (j < 10) ? 0 : ((j < 20) ? 64 : 128);
        const float* wp = &lwf[wrow * 196 + coff];
        const float* hp = &h[row * HID];
        float s = 0.f;
        #pragma unroll
        for (int q = 0; q < 16; ++q) {
            const float4 hv = *(const float4*)&hp[4 * q];
            const float4 wv = *(const float4*)&wp[4 * q];
            s += hv.x * wv.x + hv.y * wv.y + hv.z * wv.z + hv.w * wv.w;
        }
        if (j < 10)      out[row * 10 + j] = s;
        else if (j < 20) g[row * GS + (j - 10)] = s;
        else             g[row * GS + 12 + (j - 20)] = s;
    }
}

// ---------------- Kernel 3: merged edge scatter, per-(edge,col) ----------------
// 10 consecutive lanes handle one edge's 10 output cols -> same-line atomics coalesce.
__global__ __launch_bounds__(256) void k_scatter(const int* __restrict__ src1,
                                                 const int* __restrict__ dst1,
                                                 const float* __restrict__ val1, int nnz1,
                                                 const int* __restrict__ src2,
                                                 const int* __restrict__ dst2,
                                                 const float* __restrict__ val2, int nnz2,
                                                 const float* __restrict__ g,
                                                 float* __restrict__ out)
{
    const long t  = (long)blockIdx.x * 256 + threadIdx.x;
    const long n1 = 10L * nnz1;
    const int* sp; const int* dp; const float* vp; int goff; long tt;
    if (t < n1) { sp = src1; dp = dst1; vp = val1; goff = 0; tt = t; }
    else {
        tt = t - n1;
        if (tt >= 10L * nnz2) return;
        sp = src2; dp = dst2; vp = val2; goff = 12;
    }
    const int e = (int)(tt / 10);
    const int j = (int)(tt - 10L * e);
    const int   s = sp[e];
    const int   d = dp[e];
    const float v = vp[e];
    unsafeAtomicAdd(&out[(size_t)d * 10 + j], v * g[(size_t)s * GS + goff + j]);
}

extern "C" void kernel_launch(void* const* d_in, const int* in_sizes, int n_in,
                              void* d_out, int out_size, void* d_ws, size_t ws_size,
                              hipStream_t stream)
{
    const float* x    = (const float*)d_in[0];
    const float* W1   = (const float*)d_in[1];
    const float* Wf   = (const float*)d_in[2];
    const int*   src1 = (const int*)d_in[3];
    const int*   dst1 = (const int*)d_in[4];
    const float* val1 = (const float*)d_in[5];
    const int*   src2 = (const int*)d_in[6];
    const int*   dst2 = (const int*)d_in[7];
    const float* val2 = (const float*)d_in[8];
    const int nnz1 = in_sizes[3];
    const int nnz2 = in_sizes[6];
    const int n = NN;

    unsigned short* W1bf = (unsigned short*)d_ws;            // [64][512] bf16 = 64 KB
    float* h   = (float*)((char*)d_ws + 64 * KP * 2);        // [NN][64]  = 25.6 MB
    float* g   = h + (size_t)NN * HID;                       // [NN][24]  =  9.6 MB
    float* out = (float*)d_out;                              // [NN][10]

    k0_w1bf<<<128, 256, 0, stream>>>(W1, W1bf);
    k1_mfma<<<(n + 63) / 64, 256, 0, stream>>>(x, W1bf, h, n);
    k2_proj<<<(n + 7) / 8, 256, 0, stream>>>(h, Wf, out, g, n);
    const long nt = 10L * (nnz1 + nnz2);
    k_scatter<<<(int)((nt + 255) / 256), 256, 0, stream>>>(src1, dst1, val1, nnz1,
                                                           src2, dst2, val2, nnz2, g, out);
}